// Round 1
// baseline (3062.674 us; speedup 1.0000x reference)
//
#include <hip/hip_runtime.h>
#include <hip/hip_bf16.h>

// ---------------------------------------------------------------------------
// MLDecoder forward on MI355X (gfx950).
// Round 0: correctness-first. bf16 MFMA GEMMs (f32 accum), f32 residual/LN/
// softmax. Attention uses combined per-head weights:
//   Wqk_h = Wq_h @ Wk_h^T   (scores = (hn @ Wqk_h) @ kv^T * scale)
//   Wvo_h = Wv_h @ Wo_h     (out   = (softmax @ kv) @ Wvo_h)
// which removes the K/V projections entirely (725 -> ~437 GFLOP).
// ---------------------------------------------------------------------------

typedef __attribute__((ext_vector_type(8))) short short8;   // 8 bf16
typedef __attribute__((ext_vector_type(4))) short short4b;  // 4 bf16
typedef __attribute__((ext_vector_type(4))) float floatx4;

#define DEVI static __device__ __forceinline__

DEVI short f2bf(float f) {
    union { __hip_bfloat16 h; short s; } u;
    u.h = __float2bfloat16(f);
    return u.s;
}

// ---------------------------------------------------------------------------
// Generic tiled GEMM:  C[m,n] = act(alpha * sum_k A[m,k]*B[k,n] + bias[n]) + resid
//   A_MODE 0: bf16, row-major [M,K]        (element at m*lda + k)
//   A_MODE 1: f32,  row-major [M,K]
//   A_MODE 2: f32,  transposed   [K,M]     (element at k*lda + m)
//   B_MODE 0: bf16, BT layout [N,K]        (element at n*ldb + k)
//   B_MODE 1: f32,  BT layout [N,K]
//   ACT: 0 none, 1 relu, 2 gelu(tanh approx)
// Batched via blockIdx.z: z -> (outer, inner) with inner = z % inner_batch;
// operand offsets = outer*s?1 + inner*s?2 (elements).
// ---------------------------------------------------------------------------
template<int A_MODE, int B_MODE, int ACT, bool OUT_BF16>
__global__ __launch_bounds__(256)
void gemm_kernel(const void* __restrict__ Ap, const void* __restrict__ Bp,
                 const float* __restrict__ bias, const float* __restrict__ resid,
                 void* __restrict__ Cp,
                 int M, int N, int K, int lda, int ldb, int ldc, int inner_batch,
                 long sA1, long sA2, long sB1, long sB2, long sC1, long sC2,
                 float alpha)
{
    constexpr int BM = 128, BN = 128, BK = 64;
    __shared__ __align__(16) short As[BM][BK + 8];
    __shared__ __align__(16) short Bs[BN][BK + 8];

    const int z = blockIdx.z;
    const int outer = z / inner_batch;
    const int inner = z - outer * inner_batch;
    const long aoff = (long)outer * sA1 + (long)inner * sA2;
    const long boff = (long)outer * sB1 + (long)inner * sB2;
    const long coff = (long)outer * sC1 + (long)inner * sC2;
    const int m0 = blockIdx.y * BM, n0 = blockIdx.x * BN;
    const int tid = threadIdx.x;
    const int wid = tid >> 6, lane = tid & 63;
    const int wm = (wid >> 1) << 6, wn = (wid & 1) << 6;  // 2x2 wave grid, 64x64 each
    const int fr = lane & 15;                 // fragment row (A) / col (B,D)
    const int fk = (lane >> 4) << 3;          // fragment k offset (8 bf16)

    floatx4 acc[4][4] = {};

    for (int kt = 0; kt < K; kt += BK) {
        // -------- stage A tile -> As[m][k] --------
        if constexpr (A_MODE == 0) {
            const short* A = (const short*)Ap + aoff;
            const int r = tid >> 3, c8 = (tid & 7) << 3;
            #pragma unroll
            for (int i = 0; i < 4; ++i) {
                const int row = r + (i << 5);
                const int gm = m0 + row, gk = kt + c8;
                short8 v;
                if (gm < M && gk + 8 <= K) {
                    v = *(const short8*)(A + (long)gm * lda + gk);
                } else {
                    #pragma unroll
                    for (int j = 0; j < 8; ++j)
                        v[j] = (gm < M && gk + j < K) ? A[(long)gm * lda + gk + j] : (short)0;
                }
                *(short8*)(&As[row][c8]) = v;
            }
        } else if constexpr (A_MODE == 1) {
            const float* A = (const float*)Ap + aoff;
            const int r = tid >> 4, c4 = (tid & 15) << 2;
            #pragma unroll
            for (int i = 0; i < 8; ++i) {
                const int row = r + (i << 4);
                const int gm = m0 + row, gk = kt + c4;
                float v0 = 0.f, v1 = 0.f, v2 = 0.f, v3 = 0.f;
                if (gm < M) {
                    if (gk + 4 <= K) {
                        const float4 t = *(const float4*)(A + (long)gm * lda + gk);
                        v0 = t.x; v1 = t.y; v2 = t.z; v3 = t.w;
                    } else {
                        if (gk + 0 < K) v0 = A[(long)gm * lda + gk + 0];
                        if (gk + 1 < K) v1 = A[(long)gm * lda + gk + 1];
                        if (gk + 2 < K) v2 = A[(long)gm * lda + gk + 2];
                        if (gk + 3 < K) v3 = A[(long)gm * lda + gk + 3];
                    }
                }
                short4b s; s[0] = f2bf(v0); s[1] = f2bf(v1); s[2] = f2bf(v2); s[3] = f2bf(v3);
                *(short4b*)(&As[row][c4]) = s;
            }
        } else {  // A_MODE == 2: f32 [K,M]
            const float* A = (const float*)Ap + aoff;
            const int kr = tid >> 5, mc = (tid & 31) << 2;
            #pragma unroll
            for (int i = 0; i < 8; ++i) {
                const int k = kr + (i << 3);
                const int gk = kt + k;
                const int gm = m0 + mc;
                float v0 = 0.f, v1 = 0.f, v2 = 0.f, v3 = 0.f;
                if (gk < K) {
                    if (gm + 4 <= M) {
                        const float4 t = *(const float4*)(A + (long)gk * lda + gm);
                        v0 = t.x; v1 = t.y; v2 = t.z; v3 = t.w;
                    } else {
                        if (gm + 0 < M) v0 = A[(long)gk * lda + gm + 0];
                        if (gm + 1 < M) v1 = A[(long)gk * lda + gm + 1];
                        if (gm + 2 < M) v2 = A[(long)gk * lda + gm + 2];
                        if (gm + 3 < M) v3 = A[(long)gk * lda + gm + 3];
                    }
                }
                As[mc + 0][k] = f2bf(v0);
                As[mc + 1][k] = f2bf(v1);
                As[mc + 2][k] = f2bf(v2);
                As[mc + 3][k] = f2bf(v3);
            }
        }
        // -------- stage B tile -> Bs[n][k] --------
        if constexpr (B_MODE == 0) {
            const short* B = (const short*)Bp + boff;
            const int r = tid >> 3, c8 = (tid & 7) << 3;
            #pragma unroll
            for (int i = 0; i < 4; ++i) {
                const int row = r + (i << 5);
                const int gn = n0 + row, gk = kt + c8;
                short8 v;
                if (gn < N && gk + 8 <= K) {
                    v = *(const short8*)(B + (long)gn * ldb + gk);
                } else {
                    #pragma unroll
                    for (int j = 0; j < 8; ++j)
                        v[j] = (gn < N && gk + j < K) ? B[(long)gn * ldb + gk + j] : (short)0;
                }
                *(short8*)(&Bs[row][c8]) = v;
            }
        } else {  // B_MODE == 1: f32 BT [N,K]
            const float* B = (const float*)Bp + boff;
            const int r = tid >> 4, c4 = (tid & 15) << 2;
            #pragma unroll
            for (int i = 0; i < 8; ++i) {
                const int row = r + (i << 4);
                const int gn = n0 + row, gk = kt + c4;
                float v0 = 0.f, v1 = 0.f, v2 = 0.f, v3 = 0.f;
                if (gn < N) {
                    if (gk + 4 <= K) {
                        const float4 t = *(const float4*)(B + (long)gn * ldb + gk);
                        v0 = t.x; v1 = t.y; v2 = t.z; v3 = t.w;
                    } else {
                        if (gk + 0 < K) v0 = B[(long)gn * ldb + gk + 0];
                        if (gk + 1 < K) v1 = B[(long)gn * ldb + gk + 1];
                        if (gk + 2 < K) v2 = B[(long)gn * ldb + gk + 2];
                        if (gk + 3 < K) v3 = B[(long)gn * ldb + gk + 3];
                    }
                }
                short4b s; s[0] = f2bf(v0); s[1] = f2bf(v1); s[2] = f2bf(v2); s[3] = f2bf(v3);
                *(short4b*)(&Bs[row][c4]) = s;
            }
        }
        __syncthreads();

        // -------- MFMA inner loop --------
        #pragma unroll
        for (int kk = 0; kk < BK; kk += 32) {
            short8 af[4], bfv[4];
            #pragma unroll
            for (int i = 0; i < 4; ++i)
                af[i] = *(const short8*)(&As[wm + (i << 4) + fr][kk + fk]);
            #pragma unroll
            for (int j = 0; j < 4; ++j)
                bfv[j] = *(const short8*)(&Bs[wn + (j << 4) + fr][kk + fk]);
            #pragma unroll
            for (int i = 0; i < 4; ++i)
                #pragma unroll
                for (int j = 0; j < 4; ++j)
                    acc[i][j] = __builtin_amdgcn_mfma_f32_16x16x32_bf16(af[i], bfv[j], acc[i][j], 0, 0, 0);
        }
        __syncthreads();
    }

    // -------- epilogue --------
    #pragma unroll
    for (int j = 0; j < 4; ++j) {
        const int col = n0 + wn + (j << 4) + fr;
        if (col >= N) continue;
        const float bv = bias ? bias[col] : 0.0f;
        #pragma unroll
        for (int i = 0; i < 4; ++i) {
            #pragma unroll
            for (int r = 0; r < 4; ++r) {
                const int row = m0 + wm + (i << 4) + ((lane >> 4) << 2) + r;
                if (row >= M) continue;
                float v = acc[i][j][r] * alpha + bv;
                if constexpr (ACT == 1) v = fmaxf(v, 0.0f);
                if constexpr (ACT == 2) {
                    v = 0.5f * v * (1.0f + tanhf(0.7978845608028654f * (v + 0.044715f * v * v * v)));
                }
                const long ci = coff + (long)row * ldc + col;
                if (resid) v += resid[ci];
                if constexpr (OUT_BF16) ((short*)Cp)[ci] = f2bf(v);
                else                    ((float*)Cp)[ci] = v;
            }
        }
    }
}

// ---------------------------------------------------------------------------
// Batched transpose: in [R,Cc] (f32 or bf16) -> out [Cc, ldout] bf16 (out[c][r]).
// in batch stride = R*Cc, out batch stride = Cc*ldout.
// ---------------------------------------------------------------------------
template<bool IN_F32>
__global__ __launch_bounds__(256)
void transpose_kernel(const void* __restrict__ inp, short* __restrict__ outp,
                      int R, int Cc, int ldout)
{
    __shared__ short tile[64][65];
    const long in_off = (long)blockIdx.z * R * Cc;
    const long out_off = (long)blockIdx.z * Cc * ldout;
    const int bx = blockIdx.x << 6;  // input col base
    const int by = blockIdx.y << 6;  // input row base
    const int tx = threadIdx.x & 63, ty = threadIdx.x >> 6;
    #pragma unroll
    for (int i = ty; i < 64; i += 4) {
        const int r = by + i, c = bx + tx;
        short v = 0;
        if (r < R && c < Cc) {
            if constexpr (IN_F32) v = f2bf(((const float*)inp)[in_off + (long)r * Cc + c]);
            else                  v = ((const short*)inp)[in_off + (long)r * Cc + c];
        }
        tile[i][tx] = v;
    }
    __syncthreads();
    #pragma unroll
    for (int i = ty; i < 64; i += 4) {
        const int c = bx + i, r = by + tx;
        if (c < Cc && r < R) outp[out_off + (long)c * ldout + r] = tile[tx][i];
    }
}

// ---------------------------------------------------------------------------
// LayerNorm over D=768, f32 in -> bf16 out. One 192-thread block per row.
// ---------------------------------------------------------------------------
__global__ __launch_bounds__(192)
void ln_kernel(const float* __restrict__ x, const float* __restrict__ g,
               const float* __restrict__ b, short* __restrict__ out)
{
    const long row = blockIdx.x;
    const float* xr = x + row * 768;
    const int t = threadIdx.x;
    const float4 v = *(const float4*)(xr + (t << 2));
    float s  = v.x + v.y + v.z + v.w;
    float sq = v.x * v.x + v.y * v.y + v.z * v.z + v.w * v.w;
    #pragma unroll
    for (int off = 32; off; off >>= 1) {
        s  += __shfl_xor(s, off);
        sq += __shfl_xor(sq, off);
    }
    __shared__ float ss[4], ssq[4];
    const int w = t >> 6;
    if ((t & 63) == 0) { ss[w] = s; ssq[w] = sq; }
    __syncthreads();
    s  = ss[0] + ss[1] + ss[2];
    sq = ssq[0] + ssq[1] + ssq[2];
    const float mean = s * (1.0f / 768.0f);
    const float var  = sq * (1.0f / 768.0f) - mean * mean;
    const float rstd = rsqrtf(var + 1e-5f);
    const float4 gv = *(const float4*)(g + (t << 2));
    const float4 bv = *(const float4*)(b + (t << 2));
    short4b o;
    o[0] = f2bf((v.x - mean) * rstd * gv.x + bv.x);
    o[1] = f2bf((v.y - mean) * rstd * gv.y + bv.y);
    o[2] = f2bf((v.z - mean) * rstd * gv.z + bv.z);
    o[3] = f2bf((v.w - mean) * rstd * gv.w + bv.w);
    *(short4b*)(out + row * 768 + (t << 2)) = o;
}

// ---------------------------------------------------------------------------
// Row softmax: f32 scores [nrows, in_ld] -> bf16 probs [nrows, out_ld].
// One wave per row, nk <= 256.
// ---------------------------------------------------------------------------
__global__ __launch_bounds__(64)
void softmax_kernel(const float* __restrict__ s, short* __restrict__ a,
                    int nk, int in_ld, int out_ld)
{
    const long row = blockIdx.x;
    const float* sr = s + row * in_ld;
    short* ar = a + row * out_ld;
    const int t = threadIdx.x;
    const int j0 = t, j1 = t + 64, j2 = t + 128, j3 = t + 192;
    float v0 = -1e30f, v1 = -1e30f, v2 = -1e30f, v3 = -1e30f;
    if (j0 < nk) v0 = sr[j0];
    if (j1 < nk) v1 = sr[j1];
    if (j2 < nk) v2 = sr[j2];
    if (j3 < nk) v3 = sr[j3];
    float m = fmaxf(fmaxf(v0, v1), fmaxf(v2, v3));
    #pragma unroll
    for (int off = 32; off; off >>= 1) m = fmaxf(m, __shfl_xor(m, off));
    const float e0 = (j0 < nk) ? expf(v0 - m) : 0.0f;
    const float e1 = (j1 < nk) ? expf(v1 - m) : 0.0f;
    const float e2 = (j2 < nk) ? expf(v2 - m) : 0.0f;
    const float e3 = (j3 < nk) ? expf(v3 - m) : 0.0f;
    float sum = e0 + e1 + e2 + e3;
    #pragma unroll
    for (int off = 32; off; off >>= 1) sum += __shfl_xor(sum, off);
    const float inv = 1.0f / sum;
    if (j0 < nk) ar[j0] = f2bf(e0 * inv);
    if (j1 < nk) ar[j1] = f2bf(e1 * inv);
    if (j2 < nk) ar[j2] = f2bf(e2 * inv);
    if (j3 < nk) ar[j3] = f2bf(e3 * inv);
}

// ---------------------------------------------------------------------------
// h0 = broadcast(query_embed): h[b][g][d] = qe[g][d].  float4 granular.
// ---------------------------------------------------------------------------
__global__ __launch_bounds__(256)
void broadcast_kernel(const float* __restrict__ qe, float* __restrict__ h)
{
    const long i = (long)blockIdx.x * 256 + threadIdx.x;  // of 1228800 float4s
    const long src = i % 19200;                           // 100*768/4
    ((float4*)h)[i] = ((const float4*)qe)[src];
}

// ---------------------------------------------------------------------------
// GroupFC: out[b, g*10+f] = sum_d h[b,g,d]*dup_pool[g,d,f] + dup_bias.
// One wave per (b,g).
// ---------------------------------------------------------------------------
__global__ __launch_bounds__(64)
void groupfc_kernel(const float* __restrict__ h, const float* __restrict__ dp,
                    const float* __restrict__ bias, float* __restrict__ out)
{
    const int bg = blockIdx.x;
    const int g = bg % 100;
    const int t = threadIdx.x;
    const float* hr = h + (long)bg * 768;
    const float* d = dp + (long)g * 7680;
    float acc[10];
    #pragma unroll
    for (int f = 0; f < 10; ++f) acc[f] = 0.0f;
    for (int k = t; k < 768; k += 64) {
        const float hv = hr[k];
        const float* dr = d + k * 10;
        #pragma unroll
        for (int f = 0; f < 10; ++f) acc[f] += hv * dr[f];
    }
    #pragma unroll
    for (int f = 0; f < 10; ++f) {
        #pragma unroll
        for (int off = 32; off; off >>= 1) acc[f] += __shfl_xor(acc[f], off);
    }
    if (t == 0) {
        const int b = bg / 100;
        #pragma unroll
        for (int f = 0; f < 10; ++f)
            out[(long)b * 1000 + g * 10 + f] = acc[f] + bias[g * 10 + f];
    }
}

// ---------------------------------------------------------------------------
extern "C" void kernel_launch(void* const* d_in, const int* in_sizes, int n_in,
                              void* d_out, int out_size, void* d_ws, size_t ws_size,
                              hipStream_t stream)
{
    const float* x       = (const float*)d_in[0];
    const float* W_embed = (const float*)d_in[1];
    const float* b_embed = (const float*)d_in[2];
    const float* qe      = (const float*)d_in[3];
    const float* ln1_g   = (const float*)d_in[4];
    const float* ln1_b   = (const float*)d_in[5];
    const float* Wq_s    = (const float*)d_in[6];
    const float* Wk_s    = (const float*)d_in[7];
    const float* Wv_s    = (const float*)d_in[8];
    const float* Wo_s    = (const float*)d_in[9];
    const float* bo_s    = (const float*)d_in[10];
    const float* ln2_g   = (const float*)d_in[11];
    const float* ln2_b   = (const float*)d_in[12];
    const float* Wq_c    = (const float*)d_in[13];
    const float* Wk_c    = (const float*)d_in[14];
    const float* Wv_c    = (const float*)d_in[15];
    const float* Wo_c    = (const float*)d_in[16];
    const float* bo_c    = (const float*)d_in[17];
    const float* ln3_g   = (const float*)d_in[18];
    const float* ln3_b   = (const float*)d_in[19];
    const float* W1      = (const float*)d_in[20];
    const float* b1      = (const float*)d_in[21];
    const float* W2      = (const float*)d_in[22];
    const float* b2      = (const float*)d_in[23];
    const float* dpool   = (const float*)d_in[24];
    const float* dbias   = (const float*)d_in[25];

    char* base = (char*)d_ws;
    size_t off = 0;
    auto alloc = [&](size_t bytes) -> void* {
        void* p = base + off;
        off += (bytes + 255) & ~(size_t)255;
        return p;
    };
    short* ek    = (short*)alloc(64L * 196 * 768 * 2);   // emb bf16 [b][196][768]
    short* ekT   = (short*)alloc(64L * 768 * 200 * 2);   // emb^T    [b][768][200pad]
    float* h     = (float*)alloc(64L * 100 * 768 * 4);   // residual stream f32
    short* hn    = (short*)alloc(64L * 100 * 768 * 2);   // LN output bf16
    short* hnT   = (short*)alloc(64L * 768 * 104 * 2);   // hn^T [b][768][104pad]
    short* WembT = (short*)alloc(768L * 2048 * 2);
    short* W1T   = (short*)alloc(2048L * 768 * 2);
    short* W2T   = (short*)alloc(768L * 2048 * 2);
    short* WqkTs = (short*)alloc(6144L * 768 * 2);       // [h*768+e][d]
    short* WvoTs = (short*)alloc(768L * 6144 * 2);       // [d][h*768+e]
    short* WqkTc = (short*)alloc(6144L * 768 * 2);
    short* WvoTc = (short*)alloc(768L * 6144 * 2);
    short* big   = (short*)alloc(64L * 100 * 6144 * 2);  // qt, later ctx
    float* sc    = (float*)alloc(64L * 8 * 100 * 196 * 4);
    short* a16   = (short*)alloc(64L * 8 * 100 * 200 * 2);
    short* t1    = (short*)alloc(64L * 100 * 2048 * 2);
    (void)ws_size; (void)in_sizes; (void)n_in; (void)out_size;

    const float inv_sqrt_dh = 0.03608439182435161f;  // 768^-0.5

    // ---- weight prep: transposes to BT layout ----
    transpose_kernel<true><<<dim3(12, 32, 1), 256, 0, stream>>>(W_embed, WembT, 2048, 768, 2048);
    transpose_kernel<true><<<dim3(32, 12, 1), 256, 0, stream>>>(W1, W1T, 768, 2048, 768);
    transpose_kernel<true><<<dim3(12, 32, 1), 256, 0, stream>>>(W2, W2T, 2048, 768, 2048);

    // ---- combined attention weights ----
    // WqkT[h*768+e][d] = sum_f Wq[d, h*768+f] * Wk[e, h*768+f]
    gemm_kernel<1, 1, 0, true><<<dim3(6, 6, 8), 256, 0, stream>>>(
        Wk_s, Wq_s, nullptr, nullptr, WqkTs,
        768, 768, 768, 6144, 6144, 768, 8,
        0L, 768L, 0L, 768L, 0L, 768L * 768, 1.0f);
    // WvoT[d][h*768+e] = sum_f Wo[h*768+f, d] * Wv[e, h*768+f]
    gemm_kernel<2, 1, 0, true><<<dim3(6, 6, 8), 256, 0, stream>>>(
        Wo_s, Wv_s, nullptr, nullptr, WvoTs,
        768, 768, 768, 768, 6144, 6144, 8,
        0L, 768L * 768, 0L, 768L, 0L, 768L, 1.0f);
    gemm_kernel<1, 1, 0, true><<<dim3(6, 6, 8), 256, 0, stream>>>(
        Wk_c, Wq_c, nullptr, nullptr, WqkTc,
        768, 768, 768, 6144, 6144, 768, 8,
        0L, 768L, 0L, 768L, 0L, 768L * 768, 1.0f);
    gemm_kernel<2, 1, 0, true><<<dim3(6, 6, 8), 256, 0, stream>>>(
        Wo_c, Wv_c, nullptr, nullptr, WvoTc,
        768, 768, 768, 768, 6144, 6144, 8,
        0L, 768L * 768, 0L, 768L, 0L, 768L, 1.0f);

    // ---- embed: ek[b][t][d] = relu(x[b][:,t]^T @ W_embed + b_embed) ----
    gemm_kernel<2, 0, 1, true><<<dim3(6, 2, 64), 256, 0, stream>>>(
        x, WembT, b_embed, nullptr, ek,
        196, 768, 2048, 196, 2048, 768, 1,
        2048L * 196, 0L, 0L, 0L, 196L * 768, 0L, 1.0f);
    transpose_kernel<false><<<dim3(12, 4, 64), 256, 0, stream>>>(ek, ekT, 196, 768, 200);

    // ---- h0 ----
    broadcast_kernel<<<dim3(4800), 256, 0, stream>>>(qe, h);

    // ================= self-attention =================
    ln_kernel<<<dim3(6400), 192, 0, stream>>>(h, ln1_g, ln1_b, hn);
    transpose_kernel<false><<<dim3(12, 2, 64), 256, 0, stream>>>(hn, hnT, 100, 768, 104);
    // qt = hn @ Wqk   [6400, 6144]
    gemm_kernel<0, 0, 0, true><<<dim3(48, 50, 1), 256, 0, stream>>>(
        hn, WqkTs, nullptr, nullptr, big,
        6400, 6144, 768, 768, 768, 6144, 1,
        0L, 0L, 0L, 0L, 0L, 0L, 1.0f);
    // scores[b,h,q,j] = qt_h @ hn^T * scale
    gemm_kernel<0, 0, 0, false><<<dim3(1, 1, 512), 256, 0, stream>>>(
        big, hn, nullptr, nullptr, sc,
        100, 100, 768, 6144, 768, 100, 8,
        614400L, 768L, 76800L, 0L, 80000L, 10000L, inv_sqrt_dh);
    softmax_kernel<<<dim3(51200), 64, 0, stream>>>(sc, a16, 100, 100, 104);
    // ctx[b,q,h*768+e] = a @ hn
    gemm_kernel<0, 0, 0, true><<<dim3(6, 1, 512), 256, 0, stream>>>(
        a16, hnT, nullptr, nullptr, big,
        100, 768, 100, 104, 104, 6144, 8,
        83200L, 10400L, 79872L, 0L, 614400L, 768L, 1.0f);
    // h += ctx @ Wvo + bo_s
    gemm_kernel<0, 0, 0, false><<<dim3(6, 50, 1), 256, 0, stream>>>(
        big, WvoTs, bo_s, h, h,
        6400, 768, 6144, 6144, 6144, 768, 1,
        0L, 0L, 0L, 0L, 0L, 0L, 1.0f);

    // ================= cross-attention =================
    ln_kernel<<<dim3(6400), 192, 0, stream>>>(h, ln2_g, ln2_b, hn);
    gemm_kernel<0, 0, 0, true><<<dim3(48, 50, 1), 256, 0, stream>>>(
        hn, WqkTc, nullptr, nullptr, big,
        6400, 6144, 768, 768, 768, 6144, 1,
        0L, 0L, 0L, 0L, 0L, 0L, 1.0f);
    gemm_kernel<0, 0, 0, false><<<dim3(2, 1, 512), 256, 0, stream>>>(
        big, ek, nullptr, nullptr, sc,
        100, 196, 768, 6144, 768, 196, 8,
        614400L, 768L, 150528L, 0L, 156800L, 19600L, inv_sqrt_dh);
    softmax_kernel<<<dim3(51200), 64, 0, stream>>>(sc, a16, 196, 196, 200);
    gemm_kernel<0, 0, 0, true><<<dim3(6, 1, 512), 256, 0, stream>>>(
        a16, ekT, nullptr, nullptr, big,
        100, 768, 196, 200, 200, 6144, 8,
        160000L, 20000L, 153600L, 0L, 614400L, 768L, 1.0f);
    gemm_kernel<0, 0, 0, false><<<dim3(6, 50, 1), 256, 0, stream>>>(
        big, WvoTc, bo_c, h, h,
        6400, 768, 6144, 6144, 6144, 768, 1,
        0L, 0L, 0L, 0L, 0L, 0L, 1.0f);

    // ================= MLP =================
    ln_kernel<<<dim3(6400), 192, 0, stream>>>(h, ln3_g, ln3_b, hn);
    gemm_kernel<0, 0, 2, true><<<dim3(16, 50, 1), 256, 0, stream>>>(
        hn, W1T, b1, nullptr, t1,
        6400, 2048, 768, 768, 768, 2048, 1,
        0L, 0L, 0L, 0L, 0L, 0L, 1.0f);
    gemm_kernel<0, 0, 0, false><<<dim3(6, 50, 1), 256, 0, stream>>>(
        t1, W2T, b2, h, h,
        6400, 768, 2048, 2048, 2048, 768, 1,
        0L, 0L, 0L, 0L, 0L, 0L, 1.0f);

    // ================= GroupFC =================
    groupfc_kernel<<<dim3(6400), 64, 0, stream>>>(h, dpool, dbias, (float*)d_out);
}

// Round 2
// 1611.677 us; speedup vs baseline: 1.9003x; 1.9003x over previous
//
#include <hip/hip_runtime.h>
#include <hip/hip_bf16.h>

// ---------------------------------------------------------------------------
// MLDecoder forward on MI355X (gfx950).  Round 2:
//  - m97-style GEMM staging: __builtin_amdgcn_global_load_lds width=16,
//    linear [128][64] LDS (fast path when tile fully in-bounds; masked
//    fallback writes the identical layout on edge tiles).
//  - m204 bijective XCD-chunked block swizzle in the GEMM for L2 locality.
//  - all GEMMs now bf16 x bf16: attention weights pre-cast to bf16, x and
//    Wo pre-transposed (f32->bf16) so the transposed-f32 staging path is
//    gone from the hot loop.
// Combined attention weights (Wqk = Wq Wk^T, Wvo = Wv Wo) remove the K/V
// projections entirely (725 -> ~410 GFLOP).
// ---------------------------------------------------------------------------

typedef __attribute__((ext_vector_type(8))) short short8;   // 8 bf16
typedef __attribute__((ext_vector_type(4))) short short4b;  // 4 bf16
typedef __attribute__((ext_vector_type(4))) float floatx4;

#define DEVI static __device__ __forceinline__

DEVI short f2bf(float f) {
    union { __hip_bfloat16 h; short s; } u;
    u.h = __float2bfloat16(f);
    return u.s;
}

DEVI void gld_lds16(const void* g, void* l) {
    __builtin_amdgcn_global_load_lds(
        (const __attribute__((address_space(1))) void*)g,
        (__attribute__((address_space(3))) void*)l, 16, 0, 0);
}

// ---------------------------------------------------------------------------
// Tiled GEMM:  C[m,n] = act(alpha * sum_k A[m,k]*B[k,n] + bias[n]) + resid
//   A bf16 row-major [M,K] (lda), B bf16 BT layout [N,K] (ldb).
//   ACT: 0 none, 1 relu, 2 gelu.  Batched via blockIdx.z (outer/inner).
// Fast path: tile fully in-bounds -> global_load_lds dwordx4 into linear
// [128][64] LDS; else masked short8/scalar staging into the same layout.
// Block order: m204 bijective XCD-chunk swizzle over the flat launch index.
// ---------------------------------------------------------------------------
template<int ACT, bool OUT_BF16>
__global__ __launch_bounds__(256)
void gemm_kernel(const short* __restrict__ Ap, const short* __restrict__ Bp,
                 const float* __restrict__ bias, const float* __restrict__ resid,
                 void* __restrict__ Cp,
                 int M, int N, int K, int lda, int ldb, int ldc, int inner_batch,
                 long sA1, long sA2, long sB1, long sB2, long sC1, long sC2,
                 float alpha)
{
    constexpr int BM = 128, BN = 128, BK = 64;
    __shared__ __align__(16) short As[BM][BK];
    __shared__ __align__(16) short Bs[BN][BK];

    // ---- XCD-chunked bijective block swizzle (m204) ----
    const int gx = gridDim.x, gy = gridDim.y;
    const long nwg = (long)gx * gy * gridDim.z;
    const long dfl = blockIdx.x + (long)gx * (blockIdx.y + (long)gy * blockIdx.z);
    const long qch = nwg >> 3, rch = nwg & 7;
    const long xcd = dfl & 7, idx = dfl >> 3;
    const long w = (xcd < rch ? xcd * (qch + 1) : rch * (qch + 1) + (xcd - rch) * qch) + idx;
    const int bx = (int)(w % gx);
    const long wt = w / gx;
    const int by = (int)(wt % gy);
    const int bz = (int)(wt / gy);

    const int outer = bz / inner_batch;
    const int inner = bz - outer * inner_batch;
    const long aoff = (long)outer * sA1 + (long)inner * sA2;
    const long boff = (long)outer * sB1 + (long)inner * sB2;
    const long coff = (long)outer * sC1 + (long)inner * sC2;
    const int m0 = by * BM, n0 = bx * BN;
    const int tid = threadIdx.x;
    const int wid = tid >> 6, lane = tid & 63;
    const int wm = (wid >> 1) << 6, wn = (wid & 1) << 6;  // 2x2 waves, 64x64 each
    const int fr = lane & 15;                 // fragment row (A) / col (B,D)
    const int fk = (lane >> 4) << 3;          // fragment k offset (8 bf16)

    const short* A = Ap + aoff;
    const short* B = Bp + boff;
    const int rowp = tid >> 3;                // 0..31
    const int col8 = (tid & 7) << 3;          // 0..56

    floatx4 acc[4][4] = {};

    for (int kt = 0; kt < K; kt += BK) {
        const bool fastA = (m0 + BM <= M) && (kt + BK <= K);
        const bool fastB = (n0 + BN <= N) && (kt + BK <= K);

        if (fastA) {
            const short* src = A + (long)(m0 + rowp) * lda + kt + col8;
            const long rstride = (long)lda << 5;   // 32 rows
            #pragma unroll
            for (int p = 0; p < 4; ++p)
                gld_lds16(src + p * rstride, &As[(p << 5) + ((tid >> 6) << 3)][0]);
        } else {
            const int r = tid >> 3, c8 = (tid & 7) << 3;
            #pragma unroll
            for (int i = 0; i < 4; ++i) {
                const int row = r + (i << 5);
                const int gm = m0 + row, gk = kt + c8;
                short8 v;
                if (gm < M && gk + 8 <= K) {
                    v = *(const short8*)(A + (long)gm * lda + gk);
                } else {
                    #pragma unroll
                    for (int j = 0; j < 8; ++j)
                        v[j] = (gm < M && gk + j < K) ? A[(long)gm * lda + gk + j] : (short)0;
                }
                *(short8*)(&As[row][c8]) = v;
            }
        }
        if (fastB) {
            const short* src = B + (long)(n0 + rowp) * ldb + kt + col8;
            const long rstride = (long)ldb << 5;
            #pragma unroll
            for (int p = 0; p < 4; ++p)
                gld_lds16(src + p * rstride, &Bs[(p << 5) + ((tid >> 6) << 3)][0]);
        } else {
            const int r = tid >> 3, c8 = (tid & 7) << 3;
            #pragma unroll
            for (int i = 0; i < 4; ++i) {
                const int row = r + (i << 5);
                const int gn = n0 + row, gk = kt + c8;
                short8 v;
                if (gn < N && gk + 8 <= K) {
                    v = *(const short8*)(B + (long)gn * ldb + gk);
                } else {
                    #pragma unroll
                    for (int j = 0; j < 8; ++j)
                        v[j] = (gn < N && gk + j < K) ? B[(long)gn * ldb + gk + j] : (short)0;
                }
                *(short8*)(&Bs[row][c8]) = v;
            }
        }
        __syncthreads();   // drains vmcnt (global_load_lds) + lgkm before use

        #pragma unroll
        for (int kk = 0; kk < BK; kk += 32) {
            short8 af[4], bfv[4];
            #pragma unroll
            for (int i = 0; i < 4; ++i)
                af[i] = *(const short8*)(&As[wm + (i << 4) + fr][kk + fk]);
            #pragma unroll
            for (int j = 0; j < 4; ++j)
                bfv[j] = *(const short8*)(&Bs[wn + (j << 4) + fr][kk + fk]);
            #pragma unroll
            for (int i = 0; i < 4; ++i)
                #pragma unroll
                for (int j = 0; j < 4; ++j)
                    acc[i][j] = __builtin_amdgcn_mfma_f32_16x16x32_bf16(af[i], bfv[j], acc[i][j], 0, 0, 0);
        }
        __syncthreads();
    }

    // -------- epilogue --------
    #pragma unroll
    for (int j = 0; j < 4; ++j) {
        const int col = n0 + wn + (j << 4) + fr;
        if (col >= N) continue;
        const float bv = bias ? bias[col] : 0.0f;
        #pragma unroll
        for (int i = 0; i < 4; ++i) {
            #pragma unroll
            for (int r = 0; r < 4; ++r) {
                const int row = m0 + wm + (i << 4) + ((lane >> 4) << 2) + r;
                if (row >= M) continue;
                float v = acc[i][j][r] * alpha + bv;
                if constexpr (ACT == 1) v = fmaxf(v, 0.0f);
                if constexpr (ACT == 2) {
                    v = 0.5f * v * (1.0f + tanhf(0.7978845608028654f * (v + 0.044715f * v * v * v)));
                }
                const long ci = coff + (long)row * ldc + col;
                if (resid) v += resid[ci];
                if constexpr (OUT_BF16) ((short*)Cp)[ci] = f2bf(v);
                else                    ((float*)Cp)[ci] = v;
            }
        }
    }
}

// ---------------------------------------------------------------------------
// Batched transpose: in [R,Cc] (f32 or bf16) -> out [Cc, ldout] bf16.
// ---------------------------------------------------------------------------
template<bool IN_F32>
__global__ __launch_bounds__(256)
void transpose_kernel(const void* __restrict__ inp, short* __restrict__ outp,
                      int R, int Cc, int ldout)
{
    __shared__ short tile[64][65];
    const long in_off = (long)blockIdx.z * R * Cc;
    const long out_off = (long)blockIdx.z * Cc * ldout;
    const int bx = blockIdx.x << 6;  // input col base
    const int by = blockIdx.y << 6;  // input row base
    const int tx = threadIdx.x & 63, ty = threadIdx.x >> 6;
    #pragma unroll
    for (int i = ty; i < 64; i += 4) {
        const int r = by + i, c = bx + tx;
        short v = 0;
        if (r < R && c < Cc) {
            if constexpr (IN_F32) v = f2bf(((const float*)inp)[in_off + (long)r * Cc + c]);
            else                  v = ((const short*)inp)[in_off + (long)r * Cc + c];
        }
        tile[i][tx] = v;
    }
    __syncthreads();
    #pragma unroll
    for (int i = ty; i < 64; i += 4) {
        const int c = bx + i, r = by + tx;
        if (c < Cc && r < R) outp[out_off + (long)c * ldout + r] = tile[tx][i];
    }
}

// ---------------------------------------------------------------------------
// f32 -> bf16 cast, float4 granular, exact grid.
// ---------------------------------------------------------------------------
__global__ __launch_bounds__(256)
void cast_kernel(const float* __restrict__ in, short* __restrict__ out)
{
    const long i = (long)blockIdx.x * 256 + threadIdx.x;
    const float4 v = ((const float4*)in)[i];
    short4b s; s[0] = f2bf(v.x); s[1] = f2bf(v.y); s[2] = f2bf(v.z); s[3] = f2bf(v.w);
    ((short4b*)out)[i] = s;
}

// ---------------------------------------------------------------------------
// LayerNorm over D=768, f32 in -> bf16 out. One 192-thread block per row.
// ---------------------------------------------------------------------------
__global__ __launch_bounds__(192)
void ln_kernel(const float* __restrict__ x, const float* __restrict__ g,
               const float* __restrict__ b, short* __restrict__ out)
{
    const long row = blockIdx.x;
    const float* xr = x + row * 768;
    const int t = threadIdx.x;
    const float4 v = *(const float4*)(xr + (t << 2));
    float s  = v.x + v.y + v.z + v.w;
    float sq = v.x * v.x + v.y * v.y + v.z * v.z + v.w * v.w;
    #pragma unroll
    for (int off = 32; off; off >>= 1) {
        s  += __shfl_xor(s, off);
        sq += __shfl_xor(sq, off);
    }
    __shared__ float ss[4], ssq[4];
    const int w = t >> 6;
    if ((t & 63) == 0) { ss[w] = s; ssq[w] = sq; }
    __syncthreads();
    s  = ss[0] + ss[1] + ss[2];
    sq = ssq[0] + ssq[1] + ssq[2];
    const float mean = s * (1.0f / 768.0f);
    const float var  = sq * (1.0f / 768.0f) - mean * mean;
    const float rstd = rsqrtf(var + 1e-5f);
    const float4 gv = *(const float4*)(g + (t << 2));
    const float4 bv = *(const float4*)(b + (t << 2));
    short4b o;
    o[0] = f2bf((v.x - mean) * rstd * gv.x + bv.x);
    o[1] = f2bf((v.y - mean) * rstd * gv.y + bv.y);
    o[2] = f2bf((v.z - mean) * rstd * gv.z + bv.z);
    o[3] = f2bf((v.w - mean) * rstd * gv.w + bv.w);
    *(short4b*)(out + row * 768 + (t << 2)) = o;
}

// ---------------------------------------------------------------------------
// Row softmax: f32 scores [nrows, in_ld] -> bf16 probs [nrows, out_ld].
// ---------------------------------------------------------------------------
__global__ __launch_bounds__(64)
void softmax_kernel(const float* __restrict__ s, short* __restrict__ a,
                    int nk, int in_ld, int out_ld)
{
    const long row = blockIdx.x;
    const float* sr = s + row * in_ld;
    short* ar = a + row * out_ld;
    const int t = threadIdx.x;
    const int j0 = t, j1 = t + 64, j2 = t + 128, j3 = t + 192;
    float v0 = -1e30f, v1 = -1e30f, v2 = -1e30f, v3 = -1e30f;
    if (j0 < nk) v0 = sr[j0];
    if (j1 < nk) v1 = sr[j1];
    if (j2 < nk) v2 = sr[j2];
    if (j3 < nk) v3 = sr[j3];
    float m = fmaxf(fmaxf(v0, v1), fmaxf(v2, v3));
    #pragma unroll
    for (int off = 32; off; off >>= 1) m = fmaxf(m, __shfl_xor(m, off));
    const float e0 = (j0 < nk) ? expf(v0 - m) : 0.0f;
    const float e1 = (j1 < nk) ? expf(v1 - m) : 0.0f;
    const float e2 = (j2 < nk) ? expf(v2 - m) : 0.0f;
    const float e3 = (j3 < nk) ? expf(v3 - m) : 0.0f;
    float sum = e0 + e1 + e2 + e3;
    #pragma unroll
    for (int off = 32; off; off >>= 1) sum += __shfl_xor(sum, off);
    const float inv = 1.0f / sum;
    if (j0 < nk) ar[j0] = f2bf(e0 * inv);
    if (j1 < nk) ar[j1] = f2bf(e1 * inv);
    if (j2 < nk) ar[j2] = f2bf(e2 * inv);
    if (j3 < nk) ar[j3] = f2bf(e3 * inv);
}

// ---------------------------------------------------------------------------
__global__ __launch_bounds__(256)
void broadcast_kernel(const float* __restrict__ qe, float* __restrict__ h)
{
    const long i = (long)blockIdx.x * 256 + threadIdx.x;  // of 1228800 float4s
    const long src = i % 19200;                           // 100*768/4
    ((float4*)h)[i] = ((const float4*)qe)[src];
}

// ---------------------------------------------------------------------------
// GroupFC: out[b, g*10+f] = sum_d h[b,g,d]*dup_pool[g,d,f] + dup_bias.
// ---------------------------------------------------------------------------
__global__ __launch_bounds__(64)
void groupfc_kernel(const float* __restrict__ h, const float* __restrict__ dp,
                    const float* __restrict__ bias, float* __restrict__ out)
{
    const int bg = blockIdx.x;
    const int g = bg % 100;
    const int t = threadIdx.x;
    const float* hr = h + (long)bg * 768;
    const float* d = dp + (long)g * 7680;
    float acc[10];
    #pragma unroll
    for (int f = 0; f < 10; ++f) acc[f] = 0.0f;
    for (int k = t; k < 768; k += 64) {
        const float hv = hr[k];
        const float* dr = d + k * 10;
        #pragma unroll
        for (int f = 0; f < 10; ++f) acc[f] += hv * dr[f];
    }
    #pragma unroll
    for (int f = 0; f < 10; ++f) {
        #pragma unroll
        for (int off = 32; off; off >>= 1) acc[f] += __shfl_xor(acc[f], off);
    }
    if (t == 0) {
        const int b = bg / 100;
        #pragma unroll
        for (int f = 0; f < 10; ++f)
            out[(long)b * 1000 + g * 10 + f] = acc[f] + bias[g * 10 + f];
    }
}

// ---------------------------------------------------------------------------
extern "C" void kernel_launch(void* const* d_in, const int* in_sizes, int n_in,
                              void* d_out, int out_size, void* d_ws, size_t ws_size,
                              hipStream_t stream)
{
    const float* x       = (const float*)d_in[0];
    const float* W_embed = (const float*)d_in[1];
    const float* b_embed = (const float*)d_in[2];
    const float* qe      = (const float*)d_in[3];
    const float* ln1_g   = (const float*)d_in[4];
    const float* ln1_b   = (const float*)d_in[5];
    const float* Wq_s    = (const float*)d_in[6];
    const float* Wk_s    = (const float*)d_in[7];
    const float* Wv_s    = (const float*)d_in[8];
    const float* Wo_s    = (const float*)d_in[9];
    const float* bo_s    = (const float*)d_in[10];
    const float* ln2_g   = (const float*)d_in[11];
    const float* ln2_b   = (const float*)d_in[12];
    const float* Wq_c    = (const float*)d_in[13];
    const float* Wk_c    = (const float*)d_in[14];
    const float* Wv_c    = (const float*)d_in[15];
    const float* Wo_c    = (const float*)d_in[16];
    const float* bo_c    = (const float*)d_in[17];
    const float* ln3_g   = (const float*)d_in[18];
    const float* ln3_b   = (const float*)d_in[19];
    const float* W1      = (const float*)d_in[20];
    const float* b1      = (const float*)d_in[21];
    const float* W2      = (const float*)d_in[22];
    const float* b2      = (const float*)d_in[23];
    const float* dpool   = (const float*)d_in[24];
    const float* dbias   = (const float*)d_in[25];

    char* base = (char*)d_ws;
    size_t off = 0;
    auto alloc = [&](size_t bytes) -> void* {
        void* p = base + off;
        off += (bytes + 255) & ~(size_t)255;
        return p;
    };
    short* ek    = (short*)alloc(64L * 196 * 768 * 2);   // emb bf16 [b][196][768]
    short* ekT   = (short*)alloc(64L * 768 * 200 * 2);   // emb^T    [b][768][200pad]
    float* h     = (float*)alloc(64L * 100 * 768 * 4);   // residual stream f32
    short* hn    = (short*)alloc(64L * 100 * 768 * 2);   // LN output bf16
    short* hnT   = (short*)alloc(64L * 768 * 104 * 2);   // hn^T [b][768][104pad]
    short* WembT = (short*)alloc(768L * 2048 * 2);
    short* W1T   = (short*)alloc(2048L * 768 * 2);
    short* W2T   = (short*)alloc(768L * 2048 * 2);
    short* WqkTs = (short*)alloc(6144L * 768 * 2);       // [h*768+e][d]
    short* WvoTs = (short*)alloc(768L * 6144 * 2);       // [d][h*768+e]
    short* WqkTc = (short*)alloc(6144L * 768 * 2);
    short* WvoTc = (short*)alloc(768L * 6144 * 2);
    short* big   = (short*)alloc(64L * 100 * 6144 * 2);  // wgt-scratch / xT / qt / ctx
    float* sc    = (float*)alloc(64L * 8 * 100 * 196 * 4);
    short* a16   = (short*)alloc(64L * 8 * 100 * 200 * 2);
    short* t1    = (short*)alloc(64L * 100 * 2048 * 2);  // wgt-scratch / MLP hidden
    (void)ws_size; (void)in_sizes; (void)n_in; (void)out_size;

    const float inv_sqrt_dh = 0.03608439182435161f;  // 768^-0.5
    const long WSZ = 768L * 6144;                    // 4718592 elements

    // scratch aliases (valid only during weight prep)
    short* CQ  = big;             // bf16 Wq
    short* CK  = big + WSZ;       // bf16 Wk
    short* CV  = t1;              // bf16 Wv
    short* WoT = t1 + WSZ;        // bf16 Wo^T [d][h*768+f]

    // ---- weight prep ----
    transpose_kernel<true><<<dim3(12, 32, 1), 256, 0, stream>>>(W_embed, WembT, 2048, 768, 2048);
    transpose_kernel<true><<<dim3(32, 12, 1), 256, 0, stream>>>(W1, W1T, 768, 2048, 768);
    transpose_kernel<true><<<dim3(12, 32, 1), 256, 0, stream>>>(W2, W2T, 2048, 768, 2048);

    // WqkT_s[h*768+e][d] = sum_f Wq_s[d, h*768+f] * Wk_s[e, h*768+f]
    cast_kernel<<<dim3(4608), 256, 0, stream>>>(Wq_s, CQ);
    cast_kernel<<<dim3(4608), 256, 0, stream>>>(Wk_s, CK);
    gemm_kernel<0, true><<<dim3(6, 6, 8), 256, 0, stream>>>(
        CK, CQ, nullptr, nullptr, WqkTs,
        768, 768, 768, 6144, 6144, 768, 8,
        0L, 768L, 0L, 768L, 0L, 768L * 768, 1.0f);
    cast_kernel<<<dim3(4608), 256, 0, stream>>>(Wq_c, CQ);
    cast_kernel<<<dim3(4608), 256, 0, stream>>>(Wk_c, CK);
    gemm_kernel<0, true><<<dim3(6, 6, 8), 256, 0, stream>>>(
        CK, CQ, nullptr, nullptr, WqkTc,
        768, 768, 768, 6144, 6144, 768, 8,
        0L, 768L, 0L, 768L, 0L, 768L * 768, 1.0f);

    // WvoT[d][h*768+e] = sum_f WoT[d, h*768+f] * Wv[e, h*768+f]
    cast_kernel<<<dim3(4608), 256, 0, stream>>>(Wv_s, CV);
    transpose_kernel<true><<<dim3(12, 96, 1), 256, 0, stream>>>(Wo_s, WoT, 6144, 768, 6144);
    gemm_kernel<0, true><<<dim3(6, 6, 8), 256, 0, stream>>>(
        WoT, CV, nullptr, nullptr, WvoTs,
        768, 768, 768, 6144, 6144, 6144, 8,
        0L, 768L, 0L, 768L, 0L, 768L, 1.0f);
    cast_kernel<<<dim3(4608), 256, 0, stream>>>(Wv_c, CV);
    transpose_kernel<true><<<dim3(12, 96, 1), 256, 0, stream>>>(Wo_c, WoT, 6144, 768, 6144);
    gemm_kernel<0, true><<<dim3(6, 6, 8), 256, 0, stream>>>(
        WoT, CV, nullptr, nullptr, WvoTc,
        768, 768, 768, 6144, 6144, 6144, 8,
        0L, 768L, 0L, 768L, 0L, 768L, 1.0f);

    // ---- embed: xT[b][t][c] then ek = relu(xT @ WembT^T) ----
    short* xT = big;  // [b][196][2048] bf16, 51.4 MB <= big (78.6 MB)
    transpose_kernel<true><<<dim3(4, 32, 64), 256, 0, stream>>>(x, xT, 2048, 196, 2048);
    gemm_kernel<1, true><<<dim3(6, 2, 64), 256, 0, stream>>>(
        xT, WembT, b_embed, nullptr, ek,
        196, 768, 2048, 2048, 2048, 768, 1,
        196L * 2048, 0L, 0L, 0L, 196L * 768, 0L, 1.0f);
    transpose_kernel<false><<<dim3(12, 4, 64), 256, 0, stream>>>(ek, ekT, 196, 768, 200);

    // ---- h0 ----
    broadcast_kernel<<<dim3(4800), 256, 0, stream>>>(qe, h);

    // ================= self-attention =================
    ln_kernel<<<dim3(6400), 192, 0, stream>>>(h, ln1_g, ln1_b, hn);
    transpose_kernel<false><<<dim3(12, 2, 64), 256, 0, stream>>>(hn, hnT, 100, 768, 104);
    // qt = hn @ Wqk   [6400, 6144]
    gemm_kernel<0, true><<<dim3(48, 50, 1), 256, 0, stream>>>(
        hn, WqkTs, nullptr, nullptr, big,
        6400, 6144, 768, 768, 768, 6144, 1,
        0L, 0L, 0L, 0L, 0L, 0L, 1.0f);
    // scores[b,h,q,j] = qt_h @ hn^T * scale
    gemm_kernel<0, false><<<dim3(1, 1, 512), 256, 0, stream>>>(
        big, hn, nullptr, nullptr, sc,
        100, 100, 768, 6144, 768, 100, 8,
        614400L, 768L, 76800L, 0L, 80000L, 10000L, inv_sqrt_dh);
    softmax_kernel<<<dim3(51200), 64, 0, stream>>>(sc, a16, 100, 100, 104);
    // ctx[b,q,h*768+e] = a @ hn
    gemm_kernel<0, true><<<dim3(6, 1, 512), 256, 0, stream>>>(
        a16, hnT, nullptr, nullptr, big,
        100, 768, 100, 104, 104, 6144, 8,
        83200L, 10400L, 79872L, 0L, 614400L, 768L, 1.0f);
    // h += ctx @ Wvo + bo_s
    gemm_kernel<0, false><<<dim3(6, 50, 1), 256, 0, stream>>>(
        big, WvoTs, bo_s, h, h,
        6400, 768, 6144, 6144, 6144, 768, 1,
        0L, 0L, 0L, 0L, 0L, 0L, 1.0f);

    // ================= cross-attention =================
    ln_kernel<<<dim3(6400), 192, 0, stream>>>(h, ln2_g, ln2_b, hn);
    gemm_kernel<0, true><<<dim3(48, 50, 1), 256, 0, stream>>>(
        hn, WqkTc, nullptr, nullptr, big,
        6400, 6144, 768, 768, 768, 6144, 1,
        0L, 0L, 0L, 0L, 0L, 0L, 1.0f);
    gemm_kernel<0, false><<<dim3(2, 1, 512), 256, 0, stream>>>(
        big, ek, nullptr, nullptr, sc,
        100, 196, 768, 6144, 768, 196, 8,
        614400L, 768L, 150528L, 0L, 156800L, 19600L, inv_sqrt_dh);
    softmax_kernel<<<dim3(51200), 64, 0, stream>>>(sc, a16, 196, 196, 200);
    gemm_kernel<0, true><<<dim3(6, 1, 512), 256, 0, stream>>>(
        a16, ekT, nullptr, nullptr, big,
        100, 768, 196, 200, 200, 6144, 8,
        160000L, 20000L, 153600L, 0L, 614400L, 768L, 1.0f);
    gemm_kernel<0, false><<<dim3(6, 50, 1), 256, 0, stream>>>(
        big, WvoTc, bo_c, h, h,
        6400, 768, 6144, 6144, 6144, 768, 1,
        0L, 0L, 0L, 0L, 0L, 0L, 1.0f);

    // ================= MLP =================
    ln_kernel<<<dim3(6400), 192, 0, stream>>>(h, ln3_g, ln3_b, hn);
    gemm_kernel<2, true><<<dim3(16, 50, 1), 256, 0, stream>>>(
        hn, W1T, b1, nullptr, t1,
        6400, 2048, 768, 768, 768, 2048, 1,
        0L, 0L, 0L, 0L, 0L, 0L, 1.0f);
    gemm_kernel<0, false><<<dim3(6, 50, 1), 256, 0, stream>>>(
        t1, W2T, b2, h, h,
        6400, 768, 2048, 2048, 2048, 768, 1,
        0L, 0L, 0L, 0L, 0L, 0L, 1.0f);

    // ================= GroupFC =================
    groupfc_kernel<<<dim3(6400), 64, 0, stream>>>(h, dpool, dbias, (float*)d_out);
}

// Round 3
// 1058.330 us; speedup vs baseline: 2.8939x; 1.5228x over previous
//
#include <hip/hip_runtime.h>
#include <hip/hip_bf16.h>

// ---------------------------------------------------------------------------
// MLDecoder forward on MI355X (gfx950).  Round 3:
//  - Self-attention block and cross-attn query path are BATCH-INVARIANT
//    (h0 = broadcast(query_embed)): computed once on 100 rows (~420 -> ~190 GF).
//  - Self-attn uses direct q/k/v/o projections (tiny); cross-attn keeps the
//    combined weights Wqk_c = Wq Wk^T, Wvo_c = Wv Wo (removes 118G k/v projs).
//  - Split-K (via existing batching machinery) for skinny N=768 K-big GEMMs,
//    with fused reduce + bias + residual + LayerNorm kernels.
//  - Mpad/Npad padded staging: every GEMM takes the global_load_lds fast path
//    (pad reads are stale-but-finite in-ws bf16; C-writes masked by true M,N).
// ---------------------------------------------------------------------------

typedef __attribute__((ext_vector_type(8))) short short8;   // 8 bf16
typedef __attribute__((ext_vector_type(4))) short short4b;  // 4 bf16
typedef __attribute__((ext_vector_type(4))) float floatx4;

#define DEVI static __device__ __forceinline__

DEVI short f2bf(float f) {
    union { __hip_bfloat16 h; short s; } u;
    u.h = __float2bfloat16(f);
    return u.s;
}

DEVI void gld_lds16(const void* g, void* l) {
    __builtin_amdgcn_global_load_lds(
        (const __attribute__((address_space(1))) void*)g,
        (__attribute__((address_space(3))) void*)l, 16, 0, 0);
}

// ---------------------------------------------------------------------------
// Tiled GEMM:  C[m,n] = act(alpha * sum_k A[m,k]*B[k,n] + bias[n]) + resid
//   A bf16 row-major [M,K] (lda), B bf16 BT layout [N,K] (ldb).
// Mpad/Npad: staging bounds (buffers guaranteed readable & finite up to pad);
// C-write masked by true M,N.  K must be a multiple of 64 in all calls.
// Batched via blockIdx.z (outer/inner); split-K is expressed via the same
// machinery (inner = split, sA2/sB2 = K-chunk col offset, sC2 = plane stride).
// ---------------------------------------------------------------------------
template<int ACT, bool OUT_BF16>
__global__ __launch_bounds__(256)
void gemm_kernel(const short* __restrict__ Ap, const short* __restrict__ Bp,
                 const float* __restrict__ bias, const float* __restrict__ resid,
                 void* __restrict__ Cp,
                 int M, int N, int K, int Mpad, int Npad,
                 int lda, int ldb, int ldc, int inner_batch,
                 long sA1, long sA2, long sB1, long sB2, long sC1, long sC2,
                 float alpha)
{
    constexpr int BM = 128, BN = 128, BK = 64;
    __shared__ __align__(16) short As[BM][BK];
    __shared__ __align__(16) short Bs[BN][BK];

    // ---- XCD-chunked bijective block swizzle (m204) ----
    const int gx = gridDim.x, gy = gridDim.y;
    const long nwg = (long)gx * gy * gridDim.z;
    const long dfl = blockIdx.x + (long)gx * (blockIdx.y + (long)gy * blockIdx.z);
    const long qch = nwg >> 3, rch = nwg & 7;
    const long xcd = dfl & 7, idx = dfl >> 3;
    const long w = (xcd < rch ? xcd * (qch + 1) : rch * (qch + 1) + (xcd - rch) * qch) + idx;
    const int bx = (int)(w % gx);
    const long wt = w / gx;
    const int by = (int)(wt % gy);
    const int bz = (int)(wt / gy);

    const int outer = bz / inner_batch;
    const int inner = bz - outer * inner_batch;
    const long aoff = (long)outer * sA1 + (long)inner * sA2;
    const long boff = (long)outer * sB1 + (long)inner * sB2;
    const long coff = (long)outer * sC1 + (long)inner * sC2;
    const int m0 = by * BM, n0 = bx * BN;
    const int tid = threadIdx.x;
    const int wid = tid >> 6, lane = tid & 63;
    const int wm = (wid >> 1) << 6, wn = (wid & 1) << 6;  // 2x2 waves, 64x64 each
    const int fr = lane & 15;
    const int fk = (lane >> 4) << 3;

    const short* A = Ap + aoff;
    const short* B = Bp + boff;
    const int rowp = tid >> 3;                // 0..31
    const int col8 = (tid & 7) << 3;          // 0..56
    const int wrow = (tid >> 6) << 3;         // wave id * 8

    floatx4 acc[4][4] = {};

    for (int kt = 0; kt < K; kt += BK) {
        const bool fastA = (m0 + BM <= Mpad) && (kt + BK <= K);
        const bool fastB = (n0 + BN <= Npad) && (kt + BK <= K);

        if (fastA) {
            const short* src = A + (long)(m0 + rowp) * lda + kt + col8;
            const long rstride = (long)lda << 5;   // 32 rows
            #pragma unroll
            for (int p = 0; p < 4; ++p)
                gld_lds16(src + p * rstride, &As[(p << 5) + wrow][0]);
        } else {
            #pragma unroll
            for (int i = 0; i < 4; ++i) {
                const int row = rowp + (i << 5);
                const int gm = m0 + row, gk = kt + col8;
                short8 v;
                if (gm < M && gk + 8 <= K) {
                    v = *(const short8*)(A + (long)gm * lda + gk);
                } else {
                    #pragma unroll
                    for (int j = 0; j < 8; ++j)
                        v[j] = (gm < M && gk + j < K) ? A[(long)gm * lda + gk + j] : (short)0;
                }
                *(short8*)(&As[row][col8]) = v;
            }
        }
        if (fastB) {
            const short* src = B + (long)(n0 + rowp) * ldb + kt + col8;
            const long rstride = (long)ldb << 5;
            #pragma unroll
            for (int p = 0; p < 4; ++p)
                gld_lds16(src + p * rstride, &Bs[(p << 5) + wrow][0]);
        } else {
            #pragma unroll
            for (int i = 0; i < 4; ++i) {
                const int row = rowp + (i << 5);
                const int gn = n0 + row, gk = kt + col8;
                short8 v;
                if (gn < N && gk + 8 <= K) {
                    v = *(const short8*)(B + (long)gn * ldb + gk);
                } else {
                    #pragma unroll
                    for (int j = 0; j < 8; ++j)
                        v[j] = (gn < N && gk + j < K) ? B[(long)gn * ldb + gk + j] : (short)0;
                }
                *(short8*)(&Bs[row][col8]) = v;
            }
        }
        __syncthreads();

        #pragma unroll
        for (int kk = 0; kk < BK; kk += 32) {
            short8 af[4], bfv[4];
            #pragma unroll
            for (int i = 0; i < 4; ++i)
                af[i] = *(const short8*)(&As[wm + (i << 4) + fr][kk + fk]);
            #pragma unroll
            for (int j = 0; j < 4; ++j)
                bfv[j] = *(const short8*)(&Bs[wn + (j << 4) + fr][kk + fk]);
            #pragma unroll
            for (int i = 0; i < 4; ++i)
                #pragma unroll
                for (int j = 0; j < 4; ++j)
                    acc[i][j] = __builtin_amdgcn_mfma_f32_16x16x32_bf16(af[i], bfv[j], acc[i][j], 0, 0, 0);
        }
        __syncthreads();
    }

    #pragma unroll
    for (int j = 0; j < 4; ++j) {
        const int col = n0 + wn + (j << 4) + fr;
        if (col >= N) continue;
        const float bv = bias ? bias[col] : 0.0f;
        #pragma unroll
        for (int i = 0; i < 4; ++i) {
            #pragma unroll
            for (int r = 0; r < 4; ++r) {
                const int row = m0 + wm + (i << 4) + ((lane >> 4) << 2) + r;
                if (row >= M) continue;
                float v = acc[i][j][r] * alpha + bv;
                if constexpr (ACT == 1) v = fmaxf(v, 0.0f);
                if constexpr (ACT == 2) {
                    v = 0.5f * v * (1.0f + tanhf(0.7978845608028654f * (v + 0.044715f * v * v * v)));
                }
                const long ci = coff + (long)row * ldc + col;
                if (resid) v += resid[ci];
                if constexpr (OUT_BF16) ((short*)Cp)[ci] = f2bf(v);
                else                    ((float*)Cp)[ci] = v;
            }
        }
    }
}

// ---------------------------------------------------------------------------
// Batched transpose: in [R,Cc] (f32 or bf16) -> out [Cc][ldout] bf16.
// Zero-fills dest rows r in [R, ldout) (grid.y must cover ldout rows).
// ---------------------------------------------------------------------------
template<bool IN_F32>
__global__ __launch_bounds__(256)
void transpose_kernel(const void* __restrict__ inp, short* __restrict__ outp,
                      int R, int Cc, int ldout)
{
    __shared__ short tile[64][65];
    const long in_off = (long)blockIdx.z * R * Cc;
    const long out_off = (long)blockIdx.z * Cc * ldout;
    const int bx = blockIdx.x << 6;  // input col base
    const int by = blockIdx.y << 6;  // input row base
    const int tx = threadIdx.x & 63, ty = threadIdx.x >> 6;
    #pragma unroll
    for (int i = ty; i < 64; i += 4) {
        const int r = by + i, c = bx + tx;
        short v = 0;
        if (r < R && c < Cc) {
            if constexpr (IN_F32) v = f2bf(((const float*)inp)[in_off + (long)r * Cc + c]);
            else                  v = ((const short*)inp)[in_off + (long)r * Cc + c];
        }
        tile[i][tx] = v;
    }
    __syncthreads();
    #pragma unroll
    for (int i = ty; i < 64; i += 4) {
        const int c = bx + i, r = by + tx;
        if (c < Cc && r < ldout) outp[out_off + (long)c * ldout + r] = tile[tx][i];
    }
}

// ---------------------------------------------------------------------------
__global__ __launch_bounds__(256)
void cast_kernel(const float* __restrict__ in, short* __restrict__ out)
{
    const long i = (long)blockIdx.x * 256 + threadIdx.x;
    const float4 v = ((const float4*)in)[i];
    short4b s; s[0] = f2bf(v.x); s[1] = f2bf(v.y); s[2] = f2bf(v.z); s[3] = f2bf(v.w);
    ((short4b*)out)[i] = s;
}

// ---------------------------------------------------------------------------
// LayerNorm over D=768, f32 in -> bf16 out. One 192-thread block per row.
// ---------------------------------------------------------------------------
__global__ __launch_bounds__(192)
void ln_kernel(const float* __restrict__ x, const float* __restrict__ g,
               const float* __restrict__ b, short* __restrict__ out)
{
    const long row = blockIdx.x;
    const float* xr = x + row * 768;
    const int t = threadIdx.x;
    const float4 v = *(const float4*)(xr + (t << 2));
    float s  = v.x + v.y + v.z + v.w;
    float sq = v.x * v.x + v.y * v.y + v.z * v.z + v.w * v.w;
    #pragma unroll
    for (int off = 32; off; off >>= 1) {
        s  += __shfl_xor(s, off);
        sq += __shfl_xor(sq, off);
    }
    __shared__ float ss[4], ssq[4];
    const int w = t >> 6;
    if ((t & 63) == 0) { ss[w] = s; ssq[w] = sq; }
    __syncthreads();
    s  = ss[0] + ss[1] + ss[2];
    sq = ssq[0] + ssq[1] + ssq[2];
    const float mean = s * (1.0f / 768.0f);
    const float var  = sq * (1.0f / 768.0f) - mean * mean;
    const float rstd = rsqrtf(var + 1e-5f);
    const float4 gv = *(const float4*)(g + (t << 2));
    const float4 bv = *(const float4*)(b + (t << 2));
    short4b o;
    o[0] = f2bf((v.x - mean) * rstd * gv.x + bv.x);
    o[1] = f2bf((v.y - mean) * rstd * gv.y + bv.y);
    o[2] = f2bf((v.z - mean) * rstd * gv.z + bv.z);
    o[3] = f2bf((v.w - mean) * rstd * gv.w + bv.w);
    *(short4b*)(out + row * 768 + (t << 2)) = o;
}

// ---------------------------------------------------------------------------
// Split-K reduce + bias + residual (+ optional LayerNorm).
//   h_out[row] = resid[row % rmod] + bias + sum_s part[s];  hn_out = LN(h_out)
// One 192-thread block per row (768 cols).
// ---------------------------------------------------------------------------
template<bool DO_LN>
__global__ __launch_bounds__(192)
void reduce_kernel(const float* __restrict__ part, int nsplit, long pstride,
                   const float* __restrict__ resid, int rmod,
                   const float* __restrict__ bias,
                   const float* __restrict__ g, const float* __restrict__ bvec,
                   float* __restrict__ hout, short* __restrict__ hnout)
{
    const long row = blockIdx.x;
    const int t = threadIdx.x;
    const int c = t << 2;
    const float* rr = resid + (long)(row % rmod) * 768;
    float4 v = *(const float4*)(rr + c);
    const float4 bb = *(const float4*)(bias + c);
    v.x += bb.x; v.y += bb.y; v.z += bb.z; v.w += bb.w;
    for (int s = 0; s < nsplit; ++s) {
        const float4 p = *(const float4*)(part + (long)s * pstride + row * 768 + c);
        v.x += p.x; v.y += p.y; v.z += p.z; v.w += p.w;
    }
    *(float4*)(hout + row * 768 + c) = v;
    if constexpr (DO_LN) {
        float s  = v.x + v.y + v.z + v.w;
        float sq = v.x * v.x + v.y * v.y + v.z * v.z + v.w * v.w;
        #pragma unroll
        for (int off = 32; off; off >>= 1) {
            s  += __shfl_xor(s, off);
            sq += __shfl_xor(sq, off);
        }
        __shared__ float ss[4], ssq[4];
        const int wv = t >> 6;
        if ((t & 63) == 0) { ss[wv] = s; ssq[wv] = sq; }
        __syncthreads();
        s  = ss[0] + ss[1] + ss[2];
        sq = ssq[0] + ssq[1] + ssq[2];
        const float mean = s * (1.0f / 768.0f);
        const float var  = sq * (1.0f / 768.0f) - mean * mean;
        const float rstd = rsqrtf(var + 1e-5f);
        const float4 gv = *(const float4*)(g + c);
        const float4 bv = *(const float4*)(bvec + c);
        short4b o;
        o[0] = f2bf((v.x - mean) * rstd * gv.x + bv.x);
        o[1] = f2bf((v.y - mean) * rstd * gv.y + bv.y);
        o[2] = f2bf((v.z - mean) * rstd * gv.z + bv.z);
        o[3] = f2bf((v.w - mean) * rstd * gv.w + bv.w);
        *(short4b*)(hnout + row * 768 + c) = o;
    }
}

// ---------------------------------------------------------------------------
// Row softmax: f32 scores [nrows, in_ld] -> bf16 probs [nrows, out_ld].
// One wave per row (4 rows / 256-thr block).  Rows with (r % 128) >= qcap and
// cols >= nk are written as ZERO (K/M padding for downstream fast GEMMs).
// ---------------------------------------------------------------------------
__global__ __launch_bounds__(256)
void softmax_kernel(const float* __restrict__ s, short* __restrict__ a,
                    int nk, int in_ld, int out_ld, int qcap)
{
    const long r = (long)blockIdx.x * 4 + (threadIdx.x >> 6);
    const int lane = threadIdx.x & 63;
    short* ar = a + r * out_ld;
    if ((int)(r & 127) >= qcap) {
        int* ai = (int*)ar;
        for (int j = lane; j < (out_ld >> 1); j += 64) ai[j] = 0;
        return;
    }
    const float* sr = s + r * in_ld;
    float vv[4];
    #pragma unroll
    for (int i = 0; i < 4; ++i) {
        const int j = lane + (i << 6);
        vv[i] = (j < nk) ? sr[j] : -1e30f;
    }
    float m = fmaxf(fmaxf(vv[0], vv[1]), fmaxf(vv[2], vv[3]));
    #pragma unroll
    for (int off = 32; off; off >>= 1) m = fmaxf(m, __shfl_xor(m, off));
    float e[4];
    float sum = 0.0f;
    #pragma unroll
    for (int i = 0; i < 4; ++i) {
        const int j = lane + (i << 6);
        e[i] = (j < nk) ? expf(vv[i] - m) : 0.0f;
        sum += e[i];
    }
    #pragma unroll
    for (int off = 32; off; off >>= 1) sum += __shfl_xor(sum, off);
    const float inv = 1.0f / sum;
    #pragma unroll
    for (int i = 0; i < 4; ++i) {
        const int j = lane + (i << 6);
        if (j < out_ld) ar[j] = f2bf(e[i] * inv);
    }
}

// ---------------------------------------------------------------------------
// GroupFC: out[b, g*10+f] = sum_d h[b,g,d]*dup_pool[g,d,f] + dup_bias.
// ---------------------------------------------------------------------------
__global__ __launch_bounds__(64)
void groupfc_kernel(const float* __restrict__ h, const float* __restrict__ dp,
                    const float* __restrict__ bias, float* __restrict__ out)
{
    const int bg = blockIdx.x;
    const int g = bg % 100;
    const int t = threadIdx.x;
    const float* hr = h + (long)bg * 768;
    const float* d = dp + (long)g * 7680;
    float acc[10];
    #pragma unroll
    for (int f = 0; f < 10; ++f) acc[f] = 0.0f;
    for (int k = t; k < 768; k += 64) {
        const float hv = hr[k];
        const float* dr = d + k * 10;
        #pragma unroll
        for (int f = 0; f < 10; ++f) acc[f] += hv * dr[f];
    }
    #pragma unroll
    for (int f = 0; f < 10; ++f) {
        #pragma unroll
        for (int off = 32; off; off >>= 1) acc[f] += __shfl_xor(acc[f], off);
    }
    if (t == 0) {
        const int b = bg / 100;
        #pragma unroll
        for (int f = 0; f < 10; ++f)
            out[(long)b * 1000 + g * 10 + f] = acc[f] + bias[g * 10 + f];
    }
}

// ---------------------------------------------------------------------------
extern "C" void kernel_launch(void* const* d_in, const int* in_sizes, int n_in,
                              void* d_out, int out_size, void* d_ws, size_t ws_size,
                              hipStream_t stream)
{
    const float* x       = (const float*)d_in[0];
    const float* W_embed = (const float*)d_in[1];
    const float* b_embed = (const float*)d_in[2];
    const float* qe      = (const float*)d_in[3];
    const float* ln1_g   = (const float*)d_in[4];
    const float* ln1_b   = (const float*)d_in[5];
    const float* Wq_s    = (const float*)d_in[6];
    const float* Wk_s    = (const float*)d_in[7];
    const float* Wv_s    = (const float*)d_in[8];
    const float* Wo_s    = (const float*)d_in[9];
    const float* bo_s    = (const float*)d_in[10];
    const float* ln2_g   = (const float*)d_in[11];
    const float* ln2_b   = (const float*)d_in[12];
    const float* Wq_c    = (const float*)d_in[13];
    const float* Wk_c    = (const float*)d_in[14];
    const float* Wv_c    = (const float*)d_in[15];
    const float* Wo_c    = (const float*)d_in[16];
    const float* bo_c    = (const float*)d_in[17];
    const float* ln3_g   = (const float*)d_in[18];
    const float* ln3_b   = (const float*)d_in[19];
    const float* W1      = (const float*)d_in[20];
    const float* b1      = (const float*)d_in[21];
    const float* W2      = (const float*)d_in[22];
    const float* b2      = (const float*)d_in[23];
    const float* dpool   = (const float*)d_in[24];
    const float* dbias   = (const float*)d_in[25];

    char* base = (char*)d_ws;
    size_t off = 0;
    auto alloc = [&](size_t bytes) -> void* {
        void* p = base + off;
        off += (bytes + 255) & ~(size_t)255;
        return p;
    };
    short* ek    = (short*)alloc(12544L * 768 * 2);      // emb bf16 [12544][768]
    short* ekT   = (short*)alloc(64L * 768 * 256 * 2);   // emb^T [b][768][256] zero-pad
    short* big   = (short*)alloc(6400L * 6144 * 2);      // xT, then ctx_c (compact)
    char*  shr   = (char*) alloc(512L * 128 * 256 * 6);  // sc_c + a16c / casts / partials
    float* h2    = (float*)alloc(6400L * 768 * 4);       // residual stream (b-dep)
    short* hn3   = (short*)alloc(6400L * 768 * 2);
    short* t1    = (short*)alloc(6400L * 2048 * 2);
    short* WembT = (short*)alloc(768L * 2048 * 2);
    short* W1T   = (short*)alloc(2048L * 768 * 2);
    short* W2T   = (short*)alloc(768L * 2048 * 2);
    short* WqkTc = (short*)alloc(6144L * 768 * 2);       // [h][768][768] planes
    short* WvoTc = (short*)alloc(768L * 6144 * 2);
    short* WqsT  = (short*)alloc(6144L * 768 * 2);
    short* WksT  = (short*)alloc(6144L * 768 * 2);
    short* WvsT  = (short*)alloc(6144L * 768 * 2);
    short* WosT  = (short*)alloc(768L * 6144 * 2);
    short* hn1   = (short*)alloc(128L * 768 * 2);        // pad rows stale (finite)
    short* q_s   = (short*)alloc(128L * 6144 * 2);
    short* k_s   = (short*)alloc(128L * 6144 * 2);
    short* v_s   = (short*)alloc(128L * 6144 * 2);
    short* ctx_s = (short*)alloc(128L * 6144 * 2);
    short* v_sT  = (short*)alloc(6144L * 128 * 2);       // zero-pad cols >= 100
    short* qt_c  = (short*)alloc(128L * 6144 * 2);
    float* scS   = (float*)alloc(8L * 128 * 128 * 4);
    short* a16s  = (short*)alloc(8L * 128 * 128 * 2);
    float* partS = (float*)alloc(8L * 100 * 768 * 4);
    float* h1    = (float*)alloc(128L * 768 * 4);
    short* hn2   = (short*)alloc(128L * 768 * 2);
    (void)ws_size; (void)in_sizes; (void)n_in; (void)out_size;

    // shared-region aliases (phase-disjoint)
    float* sc_c  = (float*)shr;                          // [512][128][256] f32
    short* a16c  = (short*)(shr + 512L * 128 * 256 * 4); // [512][128][256] bf16
    short* CQ    = (short*)shr;                          // prep casts
    short* CK    = CQ + 4718592L;
    short* CV    = CK + 4718592L;
    short* WoTc  = CV + 4718592L;
    float* partC = (float*)shr;                          // [4][6400][768] f32

    const float scale = 0.03608439182435161f;  // 768^-0.5

    // ================= weight prep =================
    transpose_kernel<true><<<dim3(12, 32, 1), 256, 0, stream>>>(W_embed, WembT, 2048, 768, 2048);
    transpose_kernel<true><<<dim3(32, 12, 1), 256, 0, stream>>>(W1, W1T, 768, 2048, 768);
    transpose_kernel<true><<<dim3(12, 32, 1), 256, 0, stream>>>(W2, W2T, 2048, 768, 2048);
    transpose_kernel<true><<<dim3(96, 12, 1), 256, 0, stream>>>(Wq_s, WqsT, 768, 6144, 768);
    transpose_kernel<true><<<dim3(96, 12, 1), 256, 0, stream>>>(Wk_s, WksT, 768, 6144, 768);
    transpose_kernel<true><<<dim3(96, 12, 1), 256, 0, stream>>>(Wv_s, WvsT, 768, 6144, 768);
    transpose_kernel<true><<<dim3(12, 96, 1), 256, 0, stream>>>(Wo_s, WosT, 6144, 768, 6144);

    cast_kernel<<<dim3(4608), 256, 0, stream>>>(Wq_c, CQ);
    cast_kernel<<<dim3(4608), 256, 0, stream>>>(Wk_c, CK);
    // WqkTc[h][e][d] = sum_f Wq_c[d, h*768+f] * Wk_c[e, h*768+f]
    gemm_kernel<0, true><<<dim3(6, 6, 8), 256, 0, stream>>>(
        CK, CQ, nullptr, nullptr, WqkTc,
        768, 768, 768, 768, 768, 6144, 6144, 768, 8,
        0L, 768L, 0L, 768L, 0L, 589824L, 1.0f);
    cast_kernel<<<dim3(4608), 256, 0, stream>>>(Wv_c, CV);
    transpose_kernel<true><<<dim3(12, 96, 1), 256, 0, stream>>>(Wo_c, WoTc, 6144, 768, 6144);
    // WvoTc[d][h*768+e] = sum_f WoTc[d, h*768+f] * Wv_c[e, h*768+f]
    gemm_kernel<0, true><<<dim3(6, 6, 8), 256, 0, stream>>>(
        WoTc, CV, nullptr, nullptr, WvoTc,
        768, 768, 768, 768, 768, 6144, 6144, 6144, 8,
        0L, 768L, 0L, 768L, 0L, 768L, 1.0f);

    // ================= embed =================
    short* xT = big;  // [12544][2048] bf16
    transpose_kernel<true><<<dim3(4, 32, 64), 256, 0, stream>>>(x, xT, 2048, 196, 2048);
    gemm_kernel<1, true><<<dim3(6, 98, 1), 256, 0, stream>>>(
        xT, WembT, b_embed, nullptr, ek,
        12544, 768, 2048, 12544, 768, 2048, 2048, 768, 1,
        0L, 0L, 0L, 0L, 0L, 0L, 1.0f);
    transpose_kernel<false><<<dim3(12, 4, 64), 256, 0, stream>>>(ek, ekT, 196, 768, 256);

    // ================= self-attention (batch-invariant, 100 rows) ==========
    ln_kernel<<<dim3(100), 192, 0, stream>>>(qe, ln1_g, ln1_b, hn1);
    gemm_kernel<0, true><<<dim3(48, 1, 1), 256, 0, stream>>>(
        hn1, WqsT, nullptr, nullptr, q_s,
        100, 6144, 768, 128, 6144, 768, 768, 6144, 1, 0,0,0,0,0,0, 1.0f);
    gemm_kernel<0, true><<<dim3(48, 1, 1), 256, 0, stream>>>(
        hn1, WksT, nullptr, nullptr, k_s,
        100, 6144, 768, 128, 6144, 768, 768, 6144, 1, 0,0,0,0,0,0, 1.0f);
    gemm_kernel<0, true><<<dim3(48, 1, 1), 256, 0, stream>>>(
        hn1, WvsT, nullptr, nullptr, v_s,
        100, 6144, 768, 128, 6144, 768, 768, 6144, 1, 0,0,0,0,0,0, 1.0f);
    transpose_kernel<false><<<dim3(96, 2, 1), 256, 0, stream>>>(v_s, v_sT, 100, 6144, 128);
    // scores_s[h][q][j] = scale * q_s[q, h*768:] . k_s[j, h*768:]
    gemm_kernel<0, false><<<dim3(1, 1, 8), 256, 0, stream>>>(
        q_s, k_s, nullptr, nullptr, scS,
        100, 100, 768, 128, 128, 6144, 6144, 128, 8,
        0L, 768L, 0L, 768L, 0L, 16384L, scale);
    softmax_kernel<<<dim3(256), 256, 0, stream>>>(scS, a16s, 100, 128, 128, 100);
    // ctx_s[q][h*768+e] = sum_j a16s[h][q][j] * v_s[j][h*768+e]
    gemm_kernel<0, true><<<dim3(6, 1, 8), 256, 0, stream>>>(
        a16s, v_sT, nullptr, nullptr, ctx_s,
        100, 768, 128, 128, 768, 128, 128, 6144, 8,
        0L, 16384L, 0L, 98304L, 0L, 768L, 1.0f);
    // o_s partial (split-K=8 over INNER): partS[s][q][n]
    gemm_kernel<0, false><<<dim3(6, 1, 8), 256, 0, stream>>>(
        ctx_s, WosT, nullptr, nullptr, partS,
        100, 768, 768, 128, 768, 6144, 6144, 768, 8,
        0L, 768L, 0L, 768L, 0L, 76800L, 1.0f);
    // h1 = qe + o_s + bo_s;  hn2 = LN2(h1)
    reduce_kernel<true><<<dim3(100), 192, 0, stream>>>(
        partS, 8, 76800L, qe, 100, bo_s, ln2_g, ln2_b, h1, hn2);

    // ================= cross-attention =================
    gemm_kernel<0, true><<<dim3(48, 1, 1), 256, 0, stream>>>(
        hn2, WqkTc, nullptr, nullptr, qt_c,
        100, 6144, 768, 128, 6144, 768, 768, 6144, 1, 0,0,0,0,0,0, 1.0f);
    // scores_c[b,h,q,j] = scale * qt_c[q, h*768:] . ek[b*196+j, :]
    gemm_kernel<0, false><<<dim3(2, 1, 512), 256, 0, stream>>>(
        qt_c, ek, nullptr, nullptr, sc_c,
        100, 196, 768, 128, 256, 6144, 768, 256, 8,
        0L, 768L, 150528L, 0L, 262144L, 32768L, scale);
    softmax_kernel<<<dim3(16384), 256, 0, stream>>>(sc_c, a16c, 196, 256, 256, 100);
    // ctx_c[b][q][h*768+e] = sum_j a16c[b,h,q,j] * ek[b,j,e]   (compact [6400][6144])
    gemm_kernel<0, true><<<dim3(6, 1, 512), 256, 0, stream>>>(
        a16c, ekT, nullptr, nullptr, big,
        100, 768, 256, 128, 768, 256, 256, 6144, 8,
        262144L, 32768L, 196608L, 0L, 614400L, 768L, 1.0f);
    // o_c partial (split-K=4, Kc=1536): partC[s][6400][768]
    gemm_kernel<0, false><<<dim3(6, 50, 4), 256, 0, stream>>>(
        big, WvoTc, nullptr, nullptr, partC,
        6400, 768, 1536, 6400, 768, 6144, 6144, 768, 4,
        0L, 1536L, 0L, 1536L, 0L, 4915200L, 1.0f);
    // h2 = h1[q] + o_c + bo_c;  hn3 = LN3(h2)
    reduce_kernel<true><<<dim3(6400), 192, 0, stream>>>(
        partC, 4, 4915200L, h1, 100, bo_c, ln3_g, ln3_b, h2, hn3);

    // ================= MLP =================
    gemm_kernel<2, true><<<dim3(16, 50, 1), 256, 0, stream>>>(
        hn3, W1T, b1, nullptr, t1,
        6400, 2048, 768, 6400, 2048, 768, 768, 2048, 1, 0,0,0,0,0,0, 1.0f);
    // W2 partial (split-K=4, Kc=512)
    gemm_kernel<0, false><<<dim3(6, 50, 4), 256, 0, stream>>>(
        t1, W2T, nullptr, nullptr, partC,
        6400, 768, 512, 6400, 768, 2048, 2048, 768, 4,
        0L, 512L, 0L, 512L, 0L, 4915200L, 1.0f);
    // h2 += sum + b2  (in-place, no LN)
    reduce_kernel<false><<<dim3(6400), 192, 0, stream>>>(
        partC, 4, 4915200L, h2, 6400, b2, nullptr, nullptr, h2, nullptr);

    // ================= GroupFC =================
    groupfc_kernel<<<dim3(6400), 64, 0, stream>>>(h2, dpool, dbias, (float*)d_out);
}